// Round 5
// baseline (320.269 us; speedup 1.0000x reference)
//
#include <hip/hip_runtime.h>
#include <cstddef>
#include <cstdint>

static constexpr int IN_C  = 128;
static constexpr float BN_EPS = 1e-5f;
static constexpr int OUT_C = 64;

// counting-sort geometry (N=50000, E=800000)
static constexpr int CS_C = 32;       // edge chunks
static constexpr int CS_R = 8;        // node ranges
static constexpr int CS_RANGE = 6250; // max nodes per range

using bf16x8 = __attribute__((ext_vector_type(8))) short;
using f32x4  = __attribute__((ext_vector_type(4))) float;

__device__ __forceinline__ ushort f2bf(float f) {
    uint u = __float_as_uint(f);
    u += 0x7fffu + ((u >> 16) & 1u);
    return (ushort)(u >> 16);
}
__device__ __forceinline__ uint pack2(float a, float b) {
    return (uint)f2bf(a) | ((uint)f2bf(b) << 16);
}
__device__ __forceinline__ float bf_lo(uint v) { return __uint_as_float(v << 16); }
__device__ __forceinline__ float bf_hi(uint v) { return __uint_as_float(v & 0xffff0000u); }

// ---------------------------------------------------------------------------
// K1: per-(range,chunk) LDS histograms of src and dst; plain coalesced flush.
__global__ __launch_bounds__(1024) void hist_k(
    const int* __restrict__ src, const int* __restrict__ dst,
    int* __restrict__ hsrc_part, int* __restrict__ hdst_part,
    int N, int E, int chunk, int range) {
    __shared__ int hs_[CS_RANGE];
    __shared__ int hd_[CS_RANGE];
    int c = blockIdx.x & (CS_C - 1);
    int r = blockIdx.x / CS_C;
    int base = r * range;
    int hi = min(base + range, N);
    int rsz = hi - base;
    for (int j = threadIdx.x; j < rsz; j += 1024) { hs_[j] = 0; hd_[j] = 0; }
    __syncthreads();
    int e0 = c * chunk, e1 = min(e0 + chunk, E);
    for (int i = e0 + threadIdx.x; i < e1; i += 1024) {
        int s = src[i];
        if (s >= base && s < hi) atomicAdd(&hs_[s - base], 1);
        int t = dst[i];
        if (t >= base && t < hi) atomicAdd(&hd_[t - base], 1);
    }
    __syncthreads();
    for (int j = threadIdx.x; j < rsz; j += 1024) {
        hsrc_part[(size_t)c * N + base + j] = hs_[j];
        hdst_part[(size_t)c * N + base + j] = hd_[j];
    }
}

// K2: fused reduce-over-chunks -> dinv, cnt_dst, per-scanblock bsum; zero stats.
__global__ __launch_bounds__(1024) void count_k(
    const int* __restrict__ hsrc_part, const int* __restrict__ hdst_part,
    float* __restrict__ dinv, int* __restrict__ cnt_dst,
    int* __restrict__ bsum, float* __restrict__ stats, int N) {
    __shared__ int sw[16];
    int tid = threadIdx.x;
    if (blockIdx.x == 0 && tid < 256) stats[tid] = 0.f;
    int base = blockIdx.x * 4096;
    int tsum = 0;
    #pragma unroll
    for (int j = 0; j < 4; ++j) {
        int v = base + j * 1024 + tid;
        if (v < N) {
            int a = 0, b = 0;
            for (int c = 0; c < CS_C; ++c) {
                a += hsrc_part[(size_t)c * N + v];
                b += hdst_part[(size_t)c * N + v];
            }
            dinv[v] = (a > 0) ? rsqrtf((float)a) : 0.f;
            cnt_dst[v] = b;
            tsum += b;
        }
    }
    #pragma unroll
    for (int off = 1; off < 64; off <<= 1) tsum += __shfl_xor(tsum, off, 64);
    if ((tid & 63) == 0) sw[tid >> 6] = tsum;
    __syncthreads();
    if (tid == 0) {
        int a = 0;
        #pragma unroll
        for (int w = 0; w < 16; ++w) a += sw[w];
        bsum[blockIdx.x] = a;
    }
}

// K3: fused scan: row_ptr from cnt (+ bsum prefix computed in-kernel) and
// rewrite hdst_part[c][v] into per-(chunk,node) scatter base offsets.
__global__ __launch_bounds__(1024) void phase3_k(
    const int* __restrict__ cnt, const int* __restrict__ bsum,
    int* __restrict__ row_ptr, int* __restrict__ hdst_part, int n, int nb) {
    __shared__ int sm_w[16];
    __shared__ int sm_excl[16];
    __shared__ int sm_base;
    int tid = threadIdx.x;
    int lane = tid & 63, wid = tid >> 6;
    int base = blockIdx.x * 4096;
    if (tid == 0) {
        int run = 0;
        for (int b = 0; b < (int)blockIdx.x; ++b) run += bsum[b];
        sm_base = run;
        if (blockIdx.x == 0) row_ptr[0] = 0;
    }
    int i0 = base + tid * 4;
    int c0 = (i0     < n) ? cnt[i0]     : 0;
    int c1 = (i0 + 1 < n) ? cnt[i0 + 1] : 0;
    int c2 = (i0 + 2 < n) ? cnt[i0 + 2] : 0;
    int c3 = (i0 + 3 < n) ? cnt[i0 + 3] : 0;
    int tsum = c0 + c1 + c2 + c3;
    int s = tsum;
    #pragma unroll
    for (int off = 1; off < 64; off <<= 1) {
        int t = __shfl_up(s, off, 64);
        if (lane >= off) s += t;
    }
    if (lane == 63) sm_w[wid] = s;
    __syncthreads();
    if (tid == 0) {
        int acc = 0;
        #pragma unroll
        for (int w = 0; w < 16; ++w) { sm_excl[w] = acc; acc += sm_w[w]; }
    }
    __syncthreads();
    int excl = sm_base + sm_excl[wid] + (s - tsum);
    int st0 = excl, st1 = excl + c0, st2 = st1 + c1, st3 = st2 + c2;
    if (i0     < n) row_ptr[i0 + 1] = st1;
    if (i0 + 1 < n) row_ptr[i0 + 2] = st2;
    if (i0 + 2 < n) row_ptr[i0 + 3] = st3;
    if (i0 + 3 < n) row_ptr[i0 + 4] = excl + tsum;
    // rewrite chunk partials -> offsets (exclusive over chunks, base = row start)
    int r0 = st0, r1 = st1, r2 = st2, r3 = st3;
    for (int c = 0; c < CS_C; ++c) {
        size_t idx = (size_t)c * n + i0;
        if (i0 + 3 < n) {
            int4 t = *(const int4*)(hdst_part + idx);
            int4 o = make_int4(r0, r1, r2, r3);
            *(int4*)(hdst_part + idx) = o;
            r0 += t.x; r1 += t.y; r2 += t.z; r3 += t.w;
        } else {
            if (i0 < n)     { int t = hdst_part[idx];     hdst_part[idx] = r0;     r0 += t; }
            if (i0 + 1 < n) { int t = hdst_part[idx + 1]; hdst_part[idx + 1] = r1; r1 += t; }
            if (i0 + 2 < n) { int t = hdst_part[idx + 2]; hdst_part[idx + 2] = r2; r2 += t; }
        }
    }
}

// K4: scatter via LDS cursors — no global atomics.
__global__ __launch_bounds__(1024) void scatter_k(
    const int* __restrict__ src, const int* __restrict__ dst,
    const int* __restrict__ off, int* __restrict__ col,
    int N, int E, int chunk, int range) {
    __shared__ int cur[CS_RANGE];
    int c = blockIdx.x & (CS_C - 1);
    int r = blockIdx.x / CS_C;
    int base = r * range;
    int hi = min(base + range, N);
    int rsz = hi - base;
    for (int j = threadIdx.x; j < rsz; j += 1024)
        cur[j] = off[(size_t)c * N + base + j];
    __syncthreads();
    int e0 = c * chunk, e1 = min(e0 + chunk, E);
    for (int i = e0 + threadIdx.x; i < e1; i += 1024) {
        int t = dst[i];
        if (t >= base && t < hi) {
            int pos = atomicAdd(&cur[t - base], 1);
            col[pos] = src[i];
        }
    }
}

// ---------------------------------------------------------------------------
// K5: fused convert (x -> x_bf, xs_bf) + weight transpose/convert.
__global__ void convert_prep_k(const float* __restrict__ in, const float* __restrict__ dinv,
                               ushort* __restrict__ xb, ushort* __restrict__ xsb, int n64,
                               int nb_conv,
                               const float* __restrict__ W1_0, const float* __restrict__ W1_1,
                               const float* __restrict__ b1,
                               const float* __restrict__ Wmu_0, const float* __restrict__ Wmu_1,
                               const float* __restrict__ b_mu,
                               const float* __restrict__ Wls_0, const float* __restrict__ Wls_1,
                               const float* __restrict__ b_ls,
                               ushort* __restrict__ Wt1, ushort* __restrict__ Wt2,
                               float* __restrict__ bias1, float* __restrict__ bias2) {
    int bid = blockIdx.x;
    if (bid < nb_conv) {
        int i = bid * 256 + threadIdx.x;
        if (i >= n64) return;
        int row = i >> 6;
        float d = dinv[row];
        float2 v = ((const float2*)in)[i];
        ((uint*)xb)[i] = pack2(v.x, v.y);
        ((uint*)xsb)[i] = pack2(v.x * d, v.y * d);
    } else {
        int idx = (bid - nb_conv) * 256 + threadIdx.x;  // 65536
        int which = idx >> 15;
        int c = (idx >> 8) & 127;
        int k = idx & 255;
        if (which == 0) {
            float v = (k < 128) ? W1_0[k * 128 + c] : W1_1[(k - 128) * 128 + c];
            Wt1[c * 256 + k] = f2bf(v);
            if (k == 0) bias1[c] = b1[c];
        } else {
            float v;
            if (c < 64) v = (k < 128) ? Wmu_0[k * 64 + c] : Wmu_1[(k - 128) * 64 + c];
            else        v = (k < 128) ? Wls_0[k * 64 + (c - 64)] : Wls_1[(k - 128) * 64 + (c - 64)];
            Wt2[c * 256 + k] = f2bf(v);
            if (k == 0) bias2[c] = (c < 64) ? b_mu[c] : b_ls[c - 64];
        }
    }
}

// ---------------------------------------------------------------------------
// Propagate: wave per node, 4 groups x 16 lanes, unroll 4 (stride 4 per group).
#define ACC8(V)                                         \
    acc[0] += bf_lo((V).x); acc[1] += bf_hi((V).x);     \
    acc[2] += bf_lo((V).y); acc[3] += bf_hi((V).y);     \
    acc[4] += bf_lo((V).z); acc[5] += bf_hi((V).z);     \
    acc[6] += bf_lo((V).w); acc[7] += bf_hi((V).w);

__global__ __launch_bounds__(256) void propagate4_k(
    const uint4* __restrict__ xs, uint4* __restrict__ out,
    const int* __restrict__ row_ptr, const int* __restrict__ col,
    const float* __restrict__ dinv, int n) {
    int wid = (blockIdx.x * 256 + threadIdx.x) >> 6;
    if (wid >= n) return;
    int lane = threadIdx.x & 63;
    int g = lane >> 4, li = lane & 15;
    int s = row_ptr[wid], e = row_ptr[wid + 1];
    float acc[8];
    #pragma unroll
    for (int k = 0; k < 8; ++k) acc[k] = 0.f;
    int i = s + g;
    for (; i + 12 < e; i += 16) {
        int c0 = col[i];
        int c1 = col[i + 4];
        int c2 = col[i + 8];
        int c3 = col[i + 12];
        uint4 v0 = xs[(size_t)c0 * 16 + li];
        uint4 v1 = xs[(size_t)c1 * 16 + li];
        uint4 v2 = xs[(size_t)c2 * 16 + li];
        uint4 v3 = xs[(size_t)c3 * 16 + li];
        ACC8(v0); ACC8(v1); ACC8(v2); ACC8(v3);
    }
    for (; i < e; i += 4) {
        int c0 = col[i];
        uint4 v0 = xs[(size_t)c0 * 16 + li];
        ACC8(v0);
    }
    #pragma unroll
    for (int k = 0; k < 8; ++k) {
        acc[k] += __shfl_xor(acc[k], 16, 64);
        acc[k] += __shfl_xor(acc[k], 32, 64);
    }
    if (g == 0) {
        float sc = -dinv[wid];
        uint4 o;
        o.x = pack2(acc[0] * sc, acc[1] * sc);
        o.y = pack2(acc[2] * sc, acc[3] * sc);
        o.z = pack2(acc[4] * sc, acc[5] * sc);
        o.w = pack2(acc[6] * sc, acc[7] * sc);
        out[(size_t)wid * 16 + li] = o;
    }
}

// ---------------------------------------------------------------------------
// MFMA dual GEMM, BM=128: C[n,128] = [A0|A1] (bf16, K=256) @ Wt^T + bias.
// 4 waves; wave w owns rows [32w,32w+32) as two 16-row subtiles.
template <int MODE>
__global__ __launch_bounds__(256) void gemm_mfma_k(
    const ushort* __restrict__ A0, const ushort* __restrict__ A1,
    const ushort* __restrict__ Wt, const float* __restrict__ bias,
    ushort* __restrict__ Cb, float* __restrict__ Cmu, float* __restrict__ Cls, int n) {
    __shared__ ushort sA[128][32];
    __shared__ ushort sW[128][32];

    int tid = threadIdx.x;
    int block_row = blockIdx.x * 128;
    int wave = tid >> 6, lane = tid & 63;
    int col_base = lane & 15;
    int quad = lane >> 4;
    int m0 = wave * 32 + col_base;   // subtile 0 row-in-tile (lane m index)
    int m1 = m0 + 16;

    f32x4 acc0[8], acc1[8];
    #pragma unroll
    for (int t = 0; t < 8; ++t) {
        acc0[t] = (f32x4){0.f, 0.f, 0.f, 0.f};
        acc1[t] = (f32x4){0.f, 0.f, 0.f, 0.f};
    }

    for (int k0 = 0; k0 < 256; k0 += 32) {
        // stage A: 128 rows x 32 k, two passes of 256 threads x 8 bf16
        #pragma unroll
        for (int p = 0; p < 2; ++p) {
            int row = (tid >> 2) + p * 64;
            int koff = (tid & 3) * 8;
            int grow = block_row + row;
            int kc = k0 + koff;
            uint4 v = make_uint4(0, 0, 0, 0);
            if (grow < n) {
                const ushort* srcp = (kc < 128) ? (A0 + (size_t)grow * 128 + kc)
                                                : (A1 + (size_t)grow * 128 + (kc - 128));
                v = *(const uint4*)srcp;
            }
            *(uint4*)&sA[row][koff] = v;
        }
        // stage W: 128 cols x 32 k, two passes
        #pragma unroll
        for (int i = tid; i < 512; i += 256) {
            int c = i >> 2, koff = (i & 3) * 8;
            *(uint4*)&sW[c][koff] = *(const uint4*)(Wt + (size_t)c * 256 + k0 + koff);
        }
        __syncthreads();
        bf16x8 a0 = *(const bf16x8*)&sA[m0][quad * 8];
        bf16x8 a1 = *(const bf16x8*)&sA[m1][quad * 8];
        #pragma unroll
        for (int t = 0; t < 8; ++t) {
            bf16x8 bfr = *(const bf16x8*)&sW[t * 16 + col_base][quad * 8];
            acc0[t] = __builtin_amdgcn_mfma_f32_16x16x32_bf16(a0, bfr, acc0[t], 0, 0, 0);
            acc1[t] = __builtin_amdgcn_mfma_f32_16x16x32_bf16(a1, bfr, acc1[t], 0, 0, 0);
        }
        __syncthreads();
    }

    int row_l0 = wave * 32 + quad * 4;
    #pragma unroll
    for (int t = 0; t < 8; ++t) {
        int col = t * 16 + col_base;
        float b = bias[col];
        #pragma unroll
        for (int r = 0; r < 4; ++r) {
            int g0 = block_row + row_l0 + r;
            int g1 = g0 + 16;
            if (g0 < n) {
                float v = acc0[t][r] + b;
                if (MODE == 0) Cb[(size_t)g0 * 128 + col] = f2bf(v);
                else if (col < 64) Cmu[(size_t)g0 * 64 + col] = v;
                else               Cls[(size_t)g0 * 64 + (col - 64)] = v;
            }
            if (g1 < n) {
                float v = acc1[t][r] + b;
                if (MODE == 0) Cb[(size_t)g1 * 128 + col] = f2bf(v);
                else if (col < 64) Cmu[(size_t)g1 * 64 + col] = v;
                else               Cls[(size_t)g1 * 64 + (col - 64)] = v;
            }
        }
    }
}

// ---------------------------------------------------------------------------
__global__ __launch_bounds__(256) void bn_stats_k(const ushort* __restrict__ hb,
                                                  float* __restrict__ stats, int n) {
    __shared__ float sm[1024];
    int tid = threadIdx.x;
    int p = tid & 63;
    int rw = tid >> 6;
    float s0 = 0.f, q0 = 0.f, s1 = 0.f, q1 = 0.f;
    for (int r = blockIdx.x * 4 + rw; r < n; r += gridDim.x * 4) {
        uint v = ((const uint*)hb)[(size_t)r * 64 + p];
        float f0 = bf_lo(v), f1 = bf_hi(v);
        s0 += f0; q0 += f0 * f0;
        s1 += f1; q1 += f1 * f1;
    }
    sm[tid] = s0; sm[256 + tid] = q0; sm[512 + tid] = s1; sm[768 + tid] = q1;
    __syncthreads();
    if (tid < 64) {
        #pragma unroll
        for (int q = 0; q < 4; ++q) {
            float v = sm[q * 256 + tid] + sm[q * 256 + tid + 64] +
                      sm[q * 256 + tid + 128] + sm[q * 256 + tid + 192];
            int col = 2 * tid + (q >> 1);
            atomicAdd(&stats[col + ((q & 1) ? 128 : 0)], v);
        }
    }
}

// BN finalize (per-block, from stats) + affine + ReLU in place; also hs = dinv*h.
__global__ __launch_bounds__(256) void bn_apply_k(
    ushort* __restrict__ hb, ushort* __restrict__ hsb,
    const float* __restrict__ stats, const float* __restrict__ gamma,
    const float* __restrict__ beta, const float* __restrict__ dinv,
    float inv_n, int n64) {
    __shared__ float sp[256];
    int tid = threadIdx.x;
    if (tid < 128) {
        float mean = stats[tid] * inv_n;
        float var = stats[128 + tid] * inv_n - mean * mean;
        float sc = gamma[tid] * rsqrtf(var + BN_EPS);
        sp[tid] = sc;
        sp[128 + tid] = beta[tid] - mean * sc;
    }
    __syncthreads();
    int i = blockIdx.x * 256 + tid;
    if (i >= n64) return;
    int c2 = (i & 63) * 2;
    int row = i >> 6;
    uint v = ((uint*)hb)[i];
    float f0 = fmaxf(bf_lo(v) * sp[c2]     + sp[128 + c2],     0.f);
    float f1 = fmaxf(bf_hi(v) * sp[c2 + 1] + sp[128 + c2 + 1], 0.f);
    ((uint*)hb)[i] = pack2(f0, f1);
    float d = dinv[row];
    ((uint*)hsb)[i] = pack2(f0 * d, f1 * d);
}

// ---------------------------------------------------------------------------
extern "C" void kernel_launch(void* const* d_in, const int* in_sizes, int n_in,
                              void* d_out, int out_size, void* d_ws, size_t ws_size,
                              hipStream_t stream) {
    const float* x = (const float*)d_in[0];
    const int* edge_index = (const int*)d_in[1];
    const float* W1_0 = (const float*)d_in[2];
    const float* W1_1 = (const float*)d_in[3];
    const float* b1 = (const float*)d_in[4];
    const float* gamma = (const float*)d_in[5];
    const float* beta = (const float*)d_in[6];
    const float* Wmu_0 = (const float*)d_in[7];
    const float* Wmu_1 = (const float*)d_in[8];
    const float* b_mu = (const float*)d_in[9];
    const float* Wls_0 = (const float*)d_in[10];
    const float* Wls_1 = (const float*)d_in[11];
    const float* b_ls = (const float*)d_in[12];

    const int N = in_sizes[0] / IN_C;   // 50000
    const int E = in_sizes[1] / 2;      // 800000
    const int* src = edge_index;
    const int* dst = edge_index + E;

    char* w = (char*)d_ws;
    auto alloc = [&](size_t bytes) {
        char* p = w;
        w += (bytes + 15) & ~(size_t)15;
        return p;
    };
    float* stats = (float*)alloc(256 * 4);           // zeroed by count_k
    int* row_ptr = (int*)alloc((size_t)(N + 1) * 4);
    int* bsum    = (int*)alloc(64 * 4);
    float* dinv  = (float*)alloc((size_t)N * 4);
    int* cnt_dst = (int*)alloc((size_t)N * 4);
    int* col     = (int*)alloc((size_t)E * 4);
    int* hsrc_part = (int*)alloc((size_t)CS_C * N * 4);   // 6.4 MB
    int* hdst_part = (int*)alloc((size_t)CS_C * N * 4);   // 6.4 MB (-> offsets)
    ushort* x_bf  = (ushort*)alloc((size_t)N * 128 * 2);
    ushort* xs_bf = (ushort*)alloc((size_t)N * 128 * 2);  // reused as hs
    ushort* xp_bf = (ushort*)alloc((size_t)N * 128 * 2);  // reused as hp
    ushort* h_bf  = (ushort*)alloc((size_t)N * 128 * 2);
    ushort* Wt1   = (ushort*)alloc(128 * 256 * 2);
    ushort* Wt2   = (ushort*)alloc(128 * 256 * 2);
    float* bias1  = (float*)alloc(128 * 4);
    float* bias2  = (float*)alloc(128 * 4);

    ushort* hs_bf = xs_bf;
    ushort* hp_bf = xp_bf;

    float* out_mu = (float*)d_out;
    float* out_ls = out_mu + (size_t)N * OUT_C;

    int chunk = (E + CS_C - 1) / CS_C;    // 25000
    int range = (N + CS_R - 1) / CS_R;    // 6250
    int NB = (N + 4095) / 4096;           // 13 scan blocks
    int nb_conv = (N * 64 + 255) / 256;   // 12500

    hist_k<<<CS_R * CS_C, 1024, 0, stream>>>(src, dst, hsrc_part, hdst_part, N, E, chunk, range);
    count_k<<<NB, 1024, 0, stream>>>(hsrc_part, hdst_part, dinv, cnt_dst, bsum, stats, N);
    phase3_k<<<NB, 1024, 0, stream>>>(cnt_dst, bsum, row_ptr, hdst_part, N, NB);
    scatter_k<<<CS_R * CS_C, 1024, 0, stream>>>(src, dst, hdst_part, col, N, E, chunk, range);

    convert_prep_k<<<nb_conv + 256, 256, 0, stream>>>(
        x, dinv, x_bf, xs_bf, N * 64, nb_conv,
        W1_0, W1_1, b1, Wmu_0, Wmu_1, b_mu, Wls_0, Wls_1, b_ls,
        Wt1, Wt2, bias1, bias2);

    int pb = (N + 3) / 4;
    propagate4_k<<<pb, 256, 0, stream>>>((const uint4*)xs_bf, (uint4*)xp_bf,
                                         row_ptr, col, dinv, N);

    int gb = (N + 127) / 128;
    gemm_mfma_k<0><<<gb, 256, 0, stream>>>(x_bf, xp_bf, Wt1, bias1, h_bf, nullptr, nullptr, N);

    bn_stats_k<<<256, 256, 0, stream>>>(h_bf, stats, N);
    bn_apply_k<<<(N * 64 + 255) / 256, 256, 0, stream>>>(h_bf, hs_bf, stats, gamma, beta,
                                                         dinv, 1.f / (float)N, N * 64);

    propagate4_k<<<pb, 256, 0, stream>>>((const uint4*)hs_bf, (uint4*)hp_bf,
                                         row_ptr, col, dinv, N);

    gemm_mfma_k<1><<<gb, 256, 0, stream>>>(h_bf, hp_bf, Wt2, bias2, nullptr, out_mu, out_ls, N);
}

// Round 6
// 312.994 us; speedup vs baseline: 1.0232x; 1.0232x over previous
//
#include <hip/hip_runtime.h>
#include <cstddef>
#include <cstdint>

static constexpr int IN_C  = 128;
static constexpr float BN_EPS = 1e-5f;
static constexpr int OUT_C = 64;

// counting-sort geometry (N=50000, E=800000)
static constexpr int CS_C = 32;       // edge chunks
static constexpr int CS_R = 8;        // node ranges
static constexpr int CS_RANGE = 6250; // max nodes per range

using bf16x8 = __attribute__((ext_vector_type(8))) short;
using f32x4  = __attribute__((ext_vector_type(4))) float;

__device__ __forceinline__ ushort f2bf(float f) {
    uint u = __float_as_uint(f);
    u += 0x7fffu + ((u >> 16) & 1u);
    return (ushort)(u >> 16);
}
__device__ __forceinline__ uint pack2(float a, float b) {
    return (uint)f2bf(a) | ((uint)f2bf(b) << 16);
}
__device__ __forceinline__ float bf_lo(uint v) { return __uint_as_float(v << 16); }
__device__ __forceinline__ float bf_hi(uint v) { return __uint_as_float(v & 0xffff0000u); }

// ---------------------------------------------------------------------------
// K1: per-(range,chunk) LDS histograms of src and dst; plain coalesced flush.
__global__ __launch_bounds__(1024) void hist_k(
    const int* __restrict__ src, const int* __restrict__ dst,
    int* __restrict__ hsrc_part, int* __restrict__ hdst_part,
    int N, int E, int chunk, int range) {
    __shared__ int hs_[CS_RANGE];
    __shared__ int hd_[CS_RANGE];
    int c = blockIdx.x & (CS_C - 1);
    int r = blockIdx.x / CS_C;
    int base = r * range;
    int hi = min(base + range, N);
    int rsz = hi - base;
    for (int j = threadIdx.x; j < rsz; j += 1024) { hs_[j] = 0; hd_[j] = 0; }
    __syncthreads();
    int e0 = c * chunk, e1 = min(e0 + chunk, E);
    for (int i = e0 + threadIdx.x; i < e1; i += 1024) {
        int s = src[i];
        if (s >= base && s < hi) atomicAdd(&hs_[s - base], 1);
        int t = dst[i];
        if (t >= base && t < hi) atomicAdd(&hd_[t - base], 1);
    }
    __syncthreads();
    for (int j = threadIdx.x; j < rsz; j += 1024) {
        hsrc_part[(size_t)c * N + base + j] = hs_[j];
        hdst_part[(size_t)c * N + base + j] = hd_[j];
    }
}

// K2: fused reduce-over-chunks -> dinv, cnt_dst, per-scanblock bsum; zero stats.
__global__ __launch_bounds__(1024) void count_k(
    const int* __restrict__ hsrc_part, const int* __restrict__ hdst_part,
    float* __restrict__ dinv, int* __restrict__ cnt_dst,
    int* __restrict__ bsum, float* __restrict__ stats, int N) {
    __shared__ int sw[16];
    int tid = threadIdx.x;
    if (blockIdx.x == 0 && tid < 256) stats[tid] = 0.f;
    int base = blockIdx.x * 4096;
    int tsum = 0;
    #pragma unroll
    for (int j = 0; j < 4; ++j) {
        int v = base + j * 1024 + tid;
        if (v < N) {
            int a = 0, b = 0;
            for (int c = 0; c < CS_C; ++c) {
                a += hsrc_part[(size_t)c * N + v];
                b += hdst_part[(size_t)c * N + v];
            }
            dinv[v] = (a > 0) ? rsqrtf((float)a) : 0.f;
            cnt_dst[v] = b;
            tsum += b;
        }
    }
    #pragma unroll
    for (int off = 1; off < 64; off <<= 1) tsum += __shfl_xor(tsum, off, 64);
    if ((tid & 63) == 0) sw[tid >> 6] = tsum;
    __syncthreads();
    if (tid == 0) {
        int a = 0;
        #pragma unroll
        for (int w = 0; w < 16; ++w) a += sw[w];
        bsum[blockIdx.x] = a;
    }
}

// K3: fused scan: row_ptr from cnt (+ bsum prefix computed in-kernel) and
// rewrite hdst_part[c][v] into per-(chunk,node) scatter base offsets.
__global__ __launch_bounds__(1024) void phase3_k(
    const int* __restrict__ cnt, const int* __restrict__ bsum,
    int* __restrict__ row_ptr, int* __restrict__ hdst_part, int n, int nb) {
    __shared__ int sm_w[16];
    __shared__ int sm_excl[16];
    __shared__ int sm_base;
    int tid = threadIdx.x;
    int lane = tid & 63, wid = tid >> 6;
    int base = blockIdx.x * 4096;
    if (tid == 0) {
        int run = 0;
        for (int b = 0; b < (int)blockIdx.x; ++b) run += bsum[b];
        sm_base = run;
        if (blockIdx.x == 0) row_ptr[0] = 0;
    }
    int i0 = base + tid * 4;
    int c0 = (i0     < n) ? cnt[i0]     : 0;
    int c1 = (i0 + 1 < n) ? cnt[i0 + 1] : 0;
    int c2 = (i0 + 2 < n) ? cnt[i0 + 2] : 0;
    int c3 = (i0 + 3 < n) ? cnt[i0 + 3] : 0;
    int tsum = c0 + c1 + c2 + c3;
    int s = tsum;
    #pragma unroll
    for (int off = 1; off < 64; off <<= 1) {
        int t = __shfl_up(s, off, 64);
        if (lane >= off) s += t;
    }
    if (lane == 63) sm_w[wid] = s;
    __syncthreads();
    if (tid == 0) {
        int acc = 0;
        #pragma unroll
        for (int w = 0; w < 16; ++w) { sm_excl[w] = acc; acc += sm_w[w]; }
    }
    __syncthreads();
    int excl = sm_base + sm_excl[wid] + (s - tsum);
    int st0 = excl, st1 = excl + c0, st2 = st1 + c1, st3 = st2 + c2;
    if (i0     < n) row_ptr[i0 + 1] = st1;
    if (i0 + 1 < n) row_ptr[i0 + 2] = st2;
    if (i0 + 2 < n) row_ptr[i0 + 3] = st3;
    if (i0 + 3 < n) row_ptr[i0 + 4] = excl + tsum;
    // rewrite chunk partials -> offsets (exclusive over chunks, base = row start)
    int r0 = st0, r1 = st1, r2 = st2, r3 = st3;
    for (int c = 0; c < CS_C; ++c) {
        size_t idx = (size_t)c * n + i0;
        if (i0 + 3 < n) {
            int4 t = *(const int4*)(hdst_part + idx);
            int4 o = make_int4(r0, r1, r2, r3);
            *(int4*)(hdst_part + idx) = o;
            r0 += t.x; r1 += t.y; r2 += t.z; r3 += t.w;
        } else {
            if (i0 < n)     { int t = hdst_part[idx];     hdst_part[idx] = r0;     r0 += t; }
            if (i0 + 1 < n) { int t = hdst_part[idx + 1]; hdst_part[idx + 1] = r1; r1 += t; }
            if (i0 + 2 < n) { int t = hdst_part[idx + 2]; hdst_part[idx + 2] = r2; r2 += t; }
        }
    }
}

// K4: scatter via LDS cursors — no global atomics.
__global__ __launch_bounds__(1024) void scatter_k(
    const int* __restrict__ src, const int* __restrict__ dst,
    const int* __restrict__ off, int* __restrict__ col,
    int N, int E, int chunk, int range) {
    __shared__ int cur[CS_RANGE];
    int c = blockIdx.x & (CS_C - 1);
    int r = blockIdx.x / CS_C;
    int base = r * range;
    int hi = min(base + range, N);
    int rsz = hi - base;
    for (int j = threadIdx.x; j < rsz; j += 1024)
        cur[j] = off[(size_t)c * N + base + j];
    __syncthreads();
    int e0 = c * chunk, e1 = min(e0 + chunk, E);
    for (int i = e0 + threadIdx.x; i < e1; i += 1024) {
        int t = dst[i];
        if (t >= base && t < hi) {
            int pos = atomicAdd(&cur[t - base], 1);
            col[pos] = src[i];
        }
    }
}

// ---------------------------------------------------------------------------
// K5: fused convert (x -> x_bf, xs_bf) + weight transpose/convert.
__global__ void convert_prep_k(const float* __restrict__ in, const float* __restrict__ dinv,
                               ushort* __restrict__ xb, ushort* __restrict__ xsb, int n64,
                               int nb_conv,
                               const float* __restrict__ W1_0, const float* __restrict__ W1_1,
                               const float* __restrict__ b1,
                               const float* __restrict__ Wmu_0, const float* __restrict__ Wmu_1,
                               const float* __restrict__ b_mu,
                               const float* __restrict__ Wls_0, const float* __restrict__ Wls_1,
                               const float* __restrict__ b_ls,
                               ushort* __restrict__ Wt1, ushort* __restrict__ Wt2,
                               float* __restrict__ bias1, float* __restrict__ bias2) {
    int bid = blockIdx.x;
    if (bid < nb_conv) {
        int i = bid * 256 + threadIdx.x;
        if (i >= n64) return;
        int row = i >> 6;
        float d = dinv[row];
        float2 v = ((const float2*)in)[i];
        ((uint*)xb)[i] = pack2(v.x, v.y);
        ((uint*)xsb)[i] = pack2(v.x * d, v.y * d);
    } else {
        int idx = (bid - nb_conv) * 256 + threadIdx.x;  // 65536
        int which = idx >> 15;
        int c = (idx >> 8) & 127;
        int k = idx & 255;
        if (which == 0) {
            float v = (k < 128) ? W1_0[k * 128 + c] : W1_1[(k - 128) * 128 + c];
            Wt1[c * 256 + k] = f2bf(v);
            if (k == 0) bias1[c] = b1[c];
        } else {
            float v;
            if (c < 64) v = (k < 128) ? Wmu_0[k * 64 + c] : Wmu_1[(k - 128) * 64 + c];
            else        v = (k < 128) ? Wls_0[k * 64 + (c - 64)] : Wls_1[(k - 128) * 64 + (c - 64)];
            Wt2[c * 256 + k] = f2bf(v);
            if (k == 0) bias2[c] = (c < 64) ? b_mu[c] : b_ls[c - 64];
        }
    }
}

// ---------------------------------------------------------------------------
// Propagate: wave per node, 4 groups x 16 lanes, unroll 4 (stride 4 per group).
#define ACC8(V)                                         \
    acc[0] += bf_lo((V).x); acc[1] += bf_hi((V).x);     \
    acc[2] += bf_lo((V).y); acc[3] += bf_hi((V).y);     \
    acc[4] += bf_lo((V).z); acc[5] += bf_hi((V).z);     \
    acc[6] += bf_lo((V).w); acc[7] += bf_hi((V).w);

__global__ __launch_bounds__(256) void propagate4_k(
    const uint4* __restrict__ xs, uint4* __restrict__ out,
    const int* __restrict__ row_ptr, const int* __restrict__ col,
    const float* __restrict__ dinv, int n) {
    int wid = (blockIdx.x * 256 + threadIdx.x) >> 6;
    if (wid >= n) return;
    int lane = threadIdx.x & 63;
    int g = lane >> 4, li = lane & 15;
    int s = row_ptr[wid], e = row_ptr[wid + 1];
    float acc[8];
    #pragma unroll
    for (int k = 0; k < 8; ++k) acc[k] = 0.f;
    int i = s + g;
    for (; i + 12 < e; i += 16) {
        int c0 = col[i];
        int c1 = col[i + 4];
        int c2 = col[i + 8];
        int c3 = col[i + 12];
        uint4 v0 = xs[(size_t)c0 * 16 + li];
        uint4 v1 = xs[(size_t)c1 * 16 + li];
        uint4 v2 = xs[(size_t)c2 * 16 + li];
        uint4 v3 = xs[(size_t)c3 * 16 + li];
        ACC8(v0); ACC8(v1); ACC8(v2); ACC8(v3);
    }
    for (; i < e; i += 4) {
        int c0 = col[i];
        uint4 v0 = xs[(size_t)c0 * 16 + li];
        ACC8(v0);
    }
    #pragma unroll
    for (int k = 0; k < 8; ++k) {
        acc[k] += __shfl_xor(acc[k], 16, 64);
        acc[k] += __shfl_xor(acc[k], 32, 64);
    }
    if (g == 0) {
        float sc = -dinv[wid];
        uint4 o;
        o.x = pack2(acc[0] * sc, acc[1] * sc);
        o.y = pack2(acc[2] * sc, acc[3] * sc);
        o.z = pack2(acc[4] * sc, acc[5] * sc);
        o.w = pack2(acc[6] * sc, acc[7] * sc);
        out[(size_t)wid * 16 + li] = o;
    }
}

// ---------------------------------------------------------------------------
// MFMA dual GEMM, BM=64 (reverted from BM=128: 391 blocks gave 1.5 blocks/CU
// load imbalance; 782 blocks ~3/CU is faster despite 2x W-restaging).
template <int MODE>
__global__ __launch_bounds__(256) void gemm_mfma_k(
    const ushort* __restrict__ A0, const ushort* __restrict__ A1,
    const ushort* __restrict__ Wt, const float* __restrict__ bias,
    ushort* __restrict__ Cb, float* __restrict__ Cmu, float* __restrict__ Cls, int n) {
    __shared__ ushort sA[64][32];
    __shared__ ushort sW[128][32];

    int tid = threadIdx.x;
    int block_row = blockIdx.x * 64;
    int wave = tid >> 6, lane = tid & 63;
    int m_local = wave * 16 + (lane & 15);
    int quad = lane >> 4;

    f32x4 acc[8];
    #pragma unroll
    for (int t = 0; t < 8; ++t) acc[t] = (f32x4){0.f, 0.f, 0.f, 0.f};

    for (int k0 = 0; k0 < 256; k0 += 32) {
        {
            int row = tid >> 2, koff = (tid & 3) * 8;
            int grow = block_row + row;
            int kc = k0 + koff;
            uint4 v = make_uint4(0, 0, 0, 0);
            if (grow < n) {
                const ushort* srcp = (kc < 128) ? (A0 + (size_t)grow * 128 + kc)
                                                : (A1 + (size_t)grow * 128 + (kc - 128));
                v = *(const uint4*)srcp;
            }
            *(uint4*)&sA[row][koff] = v;
        }
        #pragma unroll
        for (int i = tid; i < 512; i += 256) {
            int c = i >> 2, koff = (i & 3) * 8;
            *(uint4*)&sW[c][koff] = *(const uint4*)(Wt + (size_t)c * 256 + k0 + koff);
        }
        __syncthreads();
        bf16x8 af = *(const bf16x8*)&sA[m_local][quad * 8];
        #pragma unroll
        for (int t = 0; t < 8; ++t) {
            bf16x8 bfr = *(const bf16x8*)&sW[t * 16 + (lane & 15)][quad * 8];
            acc[t] = __builtin_amdgcn_mfma_f32_16x16x32_bf16(af, bfr, acc[t], 0, 0, 0);
        }
        __syncthreads();
    }

    int col_base = lane & 15;
    int row_l = wave * 16 + quad * 4;
    #pragma unroll
    for (int t = 0; t < 8; ++t) {
        int col = t * 16 + col_base;
        float b = bias[col];
        #pragma unroll
        for (int r = 0; r < 4; ++r) {
            int grow = block_row + row_l + r;
            if (grow < n) {
                float v = acc[t][r] + b;
                if (MODE == 0) {
                    Cb[(size_t)grow * 128 + col] = f2bf(v);
                } else {
                    if (col < 64) Cmu[(size_t)grow * 64 + col] = v;
                    else          Cls[(size_t)grow * 64 + (col - 64)] = v;
                }
            }
        }
    }
}

// ---------------------------------------------------------------------------
__global__ __launch_bounds__(256) void bn_stats_k(const ushort* __restrict__ hb,
                                                  float* __restrict__ stats, int n) {
    __shared__ float sm[1024];
    int tid = threadIdx.x;
    int p = tid & 63;
    int rw = tid >> 6;
    float s0 = 0.f, q0 = 0.f, s1 = 0.f, q1 = 0.f;
    for (int r = blockIdx.x * 4 + rw; r < n; r += gridDim.x * 4) {
        uint v = ((const uint*)hb)[(size_t)r * 64 + p];
        float f0 = bf_lo(v), f1 = bf_hi(v);
        s0 += f0; q0 += f0 * f0;
        s1 += f1; q1 += f1 * f1;
    }
    sm[tid] = s0; sm[256 + tid] = q0; sm[512 + tid] = s1; sm[768 + tid] = q1;
    __syncthreads();
    if (tid < 64) {
        #pragma unroll
        for (int q = 0; q < 4; ++q) {
            float v = sm[q * 256 + tid] + sm[q * 256 + tid + 64] +
                      sm[q * 256 + tid + 128] + sm[q * 256 + tid + 192];
            int col = 2 * tid + (q >> 1);
            atomicAdd(&stats[col + ((q & 1) ? 128 : 0)], v);
        }
    }
}

// BN finalize (per-block, from stats) + affine + ReLU in place; also hs = dinv*h.
__global__ __launch_bounds__(256) void bn_apply_k(
    ushort* __restrict__ hb, ushort* __restrict__ hsb,
    const float* __restrict__ stats, const float* __restrict__ gamma,
    const float* __restrict__ beta, const float* __restrict__ dinv,
    float inv_n, int n64) {
    __shared__ float sp[256];
    int tid = threadIdx.x;
    if (tid < 128) {
        float mean = stats[tid] * inv_n;
        float var = stats[128 + tid] * inv_n - mean * mean;
        float sc = gamma[tid] * rsqrtf(var + BN_EPS);
        sp[tid] = sc;
        sp[128 + tid] = beta[tid] - mean * sc;
    }
    __syncthreads();
    int i = blockIdx.x * 256 + tid;
    if (i >= n64) return;
    int c2 = (i & 63) * 2;
    int row = i >> 6;
    uint v = ((uint*)hb)[i];
    float f0 = fmaxf(bf_lo(v) * sp[c2]     + sp[128 + c2],     0.f);
    float f1 = fmaxf(bf_hi(v) * sp[c2 + 1] + sp[128 + c2 + 1], 0.f);
    ((uint*)hb)[i] = pack2(f0, f1);
    float d = dinv[row];
    ((uint*)hsb)[i] = pack2(f0 * d, f1 * d);
}

// ---------------------------------------------------------------------------
extern "C" void kernel_launch(void* const* d_in, const int* in_sizes, int n_in,
                              void* d_out, int out_size, void* d_ws, size_t ws_size,
                              hipStream_t stream) {
    const float* x = (const float*)d_in[0];
    const int* edge_index = (const int*)d_in[1];
    const float* W1_0 = (const float*)d_in[2];
    const float* W1_1 = (const float*)d_in[3];
    const float* b1 = (const float*)d_in[4];
    const float* gamma = (const float*)d_in[5];
    const float* beta = (const float*)d_in[6];
    const float* Wmu_0 = (const float*)d_in[7];
    const float* Wmu_1 = (const float*)d_in[8];
    const float* b_mu = (const float*)d_in[9];
    const float* Wls_0 = (const float*)d_in[10];
    const float* Wls_1 = (const float*)d_in[11];
    const float* b_ls = (const float*)d_in[12];

    const int N = in_sizes[0] / IN_C;   // 50000
    const int E = in_sizes[1] / 2;      // 800000
    const int* src = edge_index;
    const int* dst = edge_index + E;

    char* w = (char*)d_ws;
    auto alloc = [&](size_t bytes) {
        char* p = w;
        w += (bytes + 15) & ~(size_t)15;
        return p;
    };
    float* stats = (float*)alloc(256 * 4);           // zeroed by count_k
    int* row_ptr = (int*)alloc((size_t)(N + 1) * 4);
    int* bsum    = (int*)alloc(64 * 4);
    float* dinv  = (float*)alloc((size_t)N * 4);
    int* cnt_dst = (int*)alloc((size_t)N * 4);
    int* col     = (int*)alloc((size_t)E * 4);
    int* hsrc_part = (int*)alloc((size_t)CS_C * N * 4);   // 6.4 MB
    int* hdst_part = (int*)alloc((size_t)CS_C * N * 4);   // 6.4 MB (-> offsets)
    ushort* x_bf  = (ushort*)alloc((size_t)N * 128 * 2);
    ushort* xs_bf = (ushort*)alloc((size_t)N * 128 * 2);  // reused as hs
    ushort* xp_bf = (ushort*)alloc((size_t)N * 128 * 2);  // reused as hp
    ushort* h_bf  = (ushort*)alloc((size_t)N * 128 * 2);
    ushort* Wt1   = (ushort*)alloc(128 * 256 * 2);
    ushort* Wt2   = (ushort*)alloc(128 * 256 * 2);
    float* bias1  = (float*)alloc(128 * 4);
    float* bias2  = (float*)alloc(128 * 4);

    ushort* hs_bf = xs_bf;
    ushort* hp_bf = xp_bf;

    float* out_mu = (float*)d_out;
    float* out_ls = out_mu + (size_t)N * OUT_C;

    int chunk = (E + CS_C - 1) / CS_C;    // 25000
    int range = (N + CS_R - 1) / CS_R;    // 6250
    int NB = (N + 4095) / 4096;           // 13 scan blocks
    int nb_conv = (N * 64 + 255) / 256;   // 12500

    hist_k<<<CS_R * CS_C, 1024, 0, stream>>>(src, dst, hsrc_part, hdst_part, N, E, chunk, range);
    count_k<<<NB, 1024, 0, stream>>>(hsrc_part, hdst_part, dinv, cnt_dst, bsum, stats, N);
    phase3_k<<<NB, 1024, 0, stream>>>(cnt_dst, bsum, row_ptr, hdst_part, N, NB);
    scatter_k<<<CS_R * CS_C, 1024, 0, stream>>>(src, dst, hdst_part, col, N, E, chunk, range);

    convert_prep_k<<<nb_conv + 256, 256, 0, stream>>>(
        x, dinv, x_bf, xs_bf, N * 64, nb_conv,
        W1_0, W1_1, b1, Wmu_0, Wmu_1, b_mu, Wls_0, Wls_1, b_ls,
        Wt1, Wt2, bias1, bias2);

    int pb = (N + 3) / 4;
    propagate4_k<<<pb, 256, 0, stream>>>((const uint4*)xs_bf, (uint4*)xp_bf,
                                         row_ptr, col, dinv, N);

    int gb = (N + 63) / 64;
    gemm_mfma_k<0><<<gb, 256, 0, stream>>>(x_bf, xp_bf, Wt1, bias1, h_bf, nullptr, nullptr, N);

    bn_stats_k<<<256, 256, 0, stream>>>(h_bf, stats, N);
    bn_apply_k<<<(N * 64 + 255) / 256, 256, 0, stream>>>(h_bf, hs_bf, stats, gamma, beta,
                                                         dinv, 1.f / (float)N, N * 64);

    propagate4_k<<<pb, 256, 0, stream>>>((const uint4*)hs_bf, (uint4*)hp_bf,
                                         row_ptr, col, dinv, N);

    gemm_mfma_k<1><<<gb, 256, 0, stream>>>(h_bf, hp_bf, Wt2, bias2, nullptr, out_mu, out_ls, N);
}

// Round 7
// 291.204 us; speedup vs baseline: 1.0998x; 1.0748x over previous
//
#include <hip/hip_runtime.h>
#include <cstddef>
#include <cstdint>

static constexpr int IN_C  = 128;
static constexpr float BN_EPS = 1e-5f;
static constexpr int OUT_C = 64;

// counting-sort geometry (N=50000, E=800000)
static constexpr int CS_C = 32;       // edge chunks
static constexpr int CS_R = 8;        // node ranges
static constexpr int CS_RANGE = 6250; // max nodes per range

using bf16x8 = __attribute__((ext_vector_type(8))) short;
using f32x4  = __attribute__((ext_vector_type(4))) float;

__device__ __forceinline__ ushort f2bf(float f) {
    uint u = __float_as_uint(f);
    u += 0x7fffu + ((u >> 16) & 1u);
    return (ushort)(u >> 16);
}
__device__ __forceinline__ uint pack2(float a, float b) {
    return (uint)f2bf(a) | ((uint)f2bf(b) << 16);
}
__device__ __forceinline__ float bf_lo(uint v) { return __uint_as_float(v << 16); }
__device__ __forceinline__ float bf_hi(uint v) { return __uint_as_float(v & 0xffff0000u); }

// LDS bank-conflict-avoiding column swizzle for [row][4 groups of 8 bf16]:
// physical group = logical group ^ ((row>>1)&3). Turns the 8-way slot clash of
// stride-64B rows into 2-way (free, m136).
__device__ __forceinline__ int swz8(int row, int g) { return (g ^ ((row >> 1) & 3)) * 8; }

// ---------------------------------------------------------------------------
// K1: per-(range,chunk) LDS histograms of src and dst; plain coalesced flush.
__global__ __launch_bounds__(1024) void hist_k(
    const int* __restrict__ src, const int* __restrict__ dst,
    int* __restrict__ hsrc_part, int* __restrict__ hdst_part,
    int N, int E, int chunk, int range) {
    __shared__ int hs_[CS_RANGE];
    __shared__ int hd_[CS_RANGE];
    int c = blockIdx.x & (CS_C - 1);
    int r = blockIdx.x / CS_C;
    int base = r * range;
    int hi = min(base + range, N);
    int rsz = hi - base;
    for (int j = threadIdx.x; j < rsz; j += 1024) { hs_[j] = 0; hd_[j] = 0; }
    __syncthreads();
    int e0 = c * chunk, e1 = min(e0 + chunk, E);
    for (int i = e0 + threadIdx.x; i < e1; i += 1024) {
        int s = src[i];
        if (s >= base && s < hi) atomicAdd(&hs_[s - base], 1);
        int t = dst[i];
        if (t >= base && t < hi) atomicAdd(&hd_[t - base], 1);
    }
    __syncthreads();
    for (int j = threadIdx.x; j < rsz; j += 1024) {
        hsrc_part[(size_t)c * N + base + j] = hs_[j];
        hdst_part[(size_t)c * N + base + j] = hd_[j];
    }
}

// K2: full-chip (196 blocks) reduce over chunks -> dinv, cnt_dst, per-block sums.
// (Was 13 blocks: 5% of chip reading 12.8 MB — hidden ~20 us serialization.)
__global__ __launch_bounds__(256) void count_k(
    const int* __restrict__ hsrc_part, const int* __restrict__ hdst_part,
    float* __restrict__ dinv, int* __restrict__ cnt_dst,
    int* __restrict__ bsum, float* __restrict__ stats, int N) {
    __shared__ int sw[4];
    int tid = threadIdx.x;
    if (blockIdx.x == 0) stats[tid] = 0.f;   // 256 floats
    int v = blockIdx.x * 256 + tid;
    int b = 0;
    if (v < N) {
        int a = 0;
        for (int c = 0; c < CS_C; ++c) {
            a += hsrc_part[(size_t)c * N + v];
            b += hdst_part[(size_t)c * N + v];
        }
        dinv[v] = (a > 0) ? rsqrtf((float)a) : 0.f;
        cnt_dst[v] = b;
    }
    int t = b;
    #pragma unroll
    for (int off = 1; off < 64; off <<= 1) t += __shfl_xor(t, off, 64);
    if ((tid & 63) == 0) sw[tid >> 6] = t;
    __syncthreads();
    if (tid == 0) bsum[blockIdx.x] = sw[0] + sw[1] + sw[2] + sw[3];
}

// K2b: 1-block exclusive scan of bsum[0..nb), nb<=256 (Hillis-Steele in LDS).
__global__ __launch_bounds__(256) void bscan_k(int* __restrict__ bsum, int nb) {
    __shared__ int sm[256];
    int tid = threadIdx.x;
    int v = (tid < nb) ? bsum[tid] : 0;
    sm[tid] = v;
    __syncthreads();
    #pragma unroll
    for (int off = 1; off < 256; off <<= 1) {
        int t = (tid >= off) ? sm[tid - off] : 0;
        __syncthreads();
        sm[tid] += t;
        __syncthreads();
    }
    if (tid < nb) bsum[tid] = sm[tid] - v;   // exclusive
}

// K3: full-chip (196 blocks): row_ptr + rewrite hdst_part into scatter offsets.
__global__ __launch_bounds__(256) void phase3_k(
    const int* __restrict__ cnt, const int* __restrict__ bsum,
    int* __restrict__ row_ptr, int* __restrict__ hdst_part, int n) {
    __shared__ int swv[4];
    int tid = threadIdx.x;
    int lane = tid & 63, wave = tid >> 6;
    int v = blockIdx.x * 256 + tid;
    int c = (v < n) ? cnt[v] : 0;
    int s = c;
    #pragma unroll
    for (int off = 1; off < 64; off <<= 1) {
        int t = __shfl_up(s, off, 64);
        if (lane >= off) s += t;
    }
    if (lane == 63) swv[wave] = s;
    __syncthreads();
    int wexcl = 0;
    for (int w = 0; w < wave; ++w) wexcl += swv[w];
    int st = bsum[blockIdx.x] + wexcl + (s - c);   // global exclusive prefix
    if (v < n) row_ptr[v + 1] = st + c;
    if (v == 0) row_ptr[0] = 0;
    int r = st;
    for (int ch = 0; ch < CS_C; ++ch) {
        size_t idx = (size_t)ch * n + v;
        if (v < n) {
            int t = hdst_part[idx];
            hdst_part[idx] = r;
            r += t;
        }
    }
}

// K4: scatter via LDS cursors — no global atomics.
__global__ __launch_bounds__(1024) void scatter_k(
    const int* __restrict__ src, const int* __restrict__ dst,
    const int* __restrict__ off, int* __restrict__ col,
    int N, int E, int chunk, int range) {
    __shared__ int cur[CS_RANGE];
    int c = blockIdx.x & (CS_C - 1);
    int r = blockIdx.x / CS_C;
    int base = r * range;
    int hi = min(base + range, N);
    int rsz = hi - base;
    for (int j = threadIdx.x; j < rsz; j += 1024)
        cur[j] = off[(size_t)c * N + base + j];
    __syncthreads();
    int e0 = c * chunk, e1 = min(e0 + chunk, E);
    for (int i = e0 + threadIdx.x; i < e1; i += 1024) {
        int t = dst[i];
        if (t >= base && t < hi) {
            int pos = atomicAdd(&cur[t - base], 1);
            col[pos] = src[i];
        }
    }
}

// ---------------------------------------------------------------------------
// K5: fused convert (x -> x_bf, xs_bf) + weight transpose/convert.
__global__ void convert_prep_k(const float* __restrict__ in, const float* __restrict__ dinv,
                               ushort* __restrict__ xb, ushort* __restrict__ xsb, int n64,
                               int nb_conv,
                               const float* __restrict__ W1_0, const float* __restrict__ W1_1,
                               const float* __restrict__ b1,
                               const float* __restrict__ Wmu_0, const float* __restrict__ Wmu_1,
                               const float* __restrict__ b_mu,
                               const float* __restrict__ Wls_0, const float* __restrict__ Wls_1,
                               const float* __restrict__ b_ls,
                               ushort* __restrict__ Wt1, ushort* __restrict__ Wt2,
                               float* __restrict__ bias1, float* __restrict__ bias2) {
    int bid = blockIdx.x;
    if (bid < nb_conv) {
        int i = bid * 256 + threadIdx.x;
        if (i >= n64) return;
        int row = i >> 6;
        float d = dinv[row];
        float2 v = ((const float2*)in)[i];
        ((uint*)xb)[i] = pack2(v.x, v.y);
        ((uint*)xsb)[i] = pack2(v.x * d, v.y * d);
    } else {
        int idx = (bid - nb_conv) * 256 + threadIdx.x;  // 65536
        int which = idx >> 15;
        int c = (idx >> 8) & 127;
        int k = idx & 255;
        if (which == 0) {
            float v = (k < 128) ? W1_0[k * 128 + c] : W1_1[(k - 128) * 128 + c];
            Wt1[c * 256 + k] = f2bf(v);
            if (k == 0) bias1[c] = b1[c];
        } else {
            float v;
            if (c < 64) v = (k < 128) ? Wmu_0[k * 64 + c] : Wmu_1[(k - 128) * 64 + c];
            else        v = (k < 128) ? Wls_0[k * 64 + (c - 64)] : Wls_1[(k - 128) * 64 + (c - 64)];
            Wt2[c * 256 + k] = f2bf(v);
            if (k == 0) bias2[c] = (c < 64) ? b_mu[c] : b_ls[c - 64];
        }
    }
}

// ---------------------------------------------------------------------------
// Propagate: wave per node, 4 groups x 16 lanes, unroll 4 (stride 4 per group).
#define ACC8(V)                                         \
    acc[0] += bf_lo((V).x); acc[1] += bf_hi((V).x);     \
    acc[2] += bf_lo((V).y); acc[3] += bf_hi((V).y);     \
    acc[4] += bf_lo((V).z); acc[5] += bf_hi((V).z);     \
    acc[6] += bf_lo((V).w); acc[7] += bf_hi((V).w);

__global__ __launch_bounds__(256) void propagate4_k(
    const uint4* __restrict__ xs, uint4* __restrict__ out,
    const int* __restrict__ row_ptr, const int* __restrict__ col,
    const float* __restrict__ dinv, int n) {
    int wid = (blockIdx.x * 256 + threadIdx.x) >> 6;
    if (wid >= n) return;
    int lane = threadIdx.x & 63;
    int g = lane >> 4, li = lane & 15;
    int s = row_ptr[wid], e = row_ptr[wid + 1];
    float acc[8];
    #pragma unroll
    for (int k = 0; k < 8; ++k) acc[k] = 0.f;
    int i = s + g;
    for (; i + 12 < e; i += 16) {
        int c0 = col[i];
        int c1 = col[i + 4];
        int c2 = col[i + 8];
        int c3 = col[i + 12];
        uint4 v0 = xs[(size_t)c0 * 16 + li];
        uint4 v1 = xs[(size_t)c1 * 16 + li];
        uint4 v2 = xs[(size_t)c2 * 16 + li];
        uint4 v3 = xs[(size_t)c3 * 16 + li];
        ACC8(v0); ACC8(v1); ACC8(v2); ACC8(v3);
    }
    for (; i < e; i += 4) {
        int c0 = col[i];
        uint4 v0 = xs[(size_t)c0 * 16 + li];
        ACC8(v0);
    }
    #pragma unroll
    for (int k = 0; k < 8; ++k) {
        acc[k] += __shfl_xor(acc[k], 16, 64);
        acc[k] += __shfl_xor(acc[k], 32, 64);
    }
    if (g == 0) {
        float sc = -dinv[wid];
        uint4 o;
        o.x = pack2(acc[0] * sc, acc[1] * sc);
        o.y = pack2(acc[2] * sc, acc[3] * sc);
        o.z = pack2(acc[4] * sc, acc[5] * sc);
        o.w = pack2(acc[6] * sc, acc[7] * sc);
        out[(size_t)wid * 16 + li] = o;
    }
}

// ---------------------------------------------------------------------------
// MFMA dual GEMM, BM=64 (do NOT raise to 128: 391 blocks = 1.5/CU imbalance
// regressed round 5; 782 blocks ~3/CU wins). LDS columns XOR-swizzled (swz8).
// MODE 0 additionally accumulates BN column stats (sum, sumsq) from fp32 acc.
template <int MODE>
__global__ __launch_bounds__(256) void gemm_mfma_k(
    const ushort* __restrict__ A0, const ushort* __restrict__ A1,
    const ushort* __restrict__ Wt, const float* __restrict__ bias,
    ushort* __restrict__ Cb, float* __restrict__ Cmu, float* __restrict__ Cls,
    float* __restrict__ stats, int n) {
    __shared__ ushort sA[64][32];
    __shared__ ushort sW[128][32];
    __shared__ float smS[4][128];
    __shared__ float smQ[4][128];

    int tid = threadIdx.x;
    int block_row = blockIdx.x * 64;
    int wave = tid >> 6, lane = tid & 63;
    int col_base = lane & 15;
    int quad = lane >> 4;
    int m_local = wave * 16 + col_base;

    f32x4 acc[8];
    #pragma unroll
    for (int t = 0; t < 8; ++t) acc[t] = (f32x4){0.f, 0.f, 0.f, 0.f};

    for (int k0 = 0; k0 < 256; k0 += 32) {
        {
            int row = tid >> 2, g = tid & 3;
            int grow = block_row + row;
            int kc = k0 + g * 8;
            uint4 v = make_uint4(0, 0, 0, 0);
            if (grow < n) {
                const ushort* srcp = (kc < 128) ? (A0 + (size_t)grow * 128 + kc)
                                                : (A1 + (size_t)grow * 128 + (kc - 128));
                v = *(const uint4*)srcp;
            }
            *(uint4*)&sA[row][swz8(row, g)] = v;
        }
        #pragma unroll
        for (int i = tid; i < 512; i += 256) {
            int c = i >> 2, g = i & 3;
            *(uint4*)&sW[c][swz8(c, g)] = *(const uint4*)(Wt + (size_t)c * 256 + k0 + g * 8);
        }
        __syncthreads();
        bf16x8 af = *(const bf16x8*)&sA[m_local][swz8(m_local, quad)];
        #pragma unroll
        for (int t = 0; t < 8; ++t) {
            int wr = t * 16 + col_base;
            bf16x8 bfr = *(const bf16x8*)&sW[wr][swz8(wr, quad)];
            acc[t] = __builtin_amdgcn_mfma_f32_16x16x32_bf16(af, bfr, acc[t], 0, 0, 0);
        }
        __syncthreads();
    }

    int row_l = wave * 16 + quad * 4;
    #pragma unroll
    for (int t = 0; t < 8; ++t) {
        int col = t * 16 + col_base;
        float b = bias[col];
        float s = 0.f, q = 0.f;
        #pragma unroll
        for (int r = 0; r < 4; ++r) {
            int grow = block_row + row_l + r;
            if (grow < n) {
                float v = acc[t][r] + b;
                if (MODE == 0) {
                    Cb[(size_t)grow * 128 + col] = f2bf(v);
                    s += v; q += v * v;
                } else {
                    if (col < 64) Cmu[(size_t)grow * 64 + col] = v;
                    else          Cls[(size_t)grow * 64 + (col - 64)] = v;
                }
            }
        }
        if (MODE == 0) {
            s += __shfl_xor(s, 16, 64); s += __shfl_xor(s, 32, 64);
            q += __shfl_xor(q, 16, 64); q += __shfl_xor(q, 32, 64);
            if (quad == 0) { smS[wave][col] = s; smQ[wave][col] = q; }
        }
    }
    if (MODE == 0) {
        __syncthreads();
        if (tid < 128) {
            float s = smS[0][tid] + smS[1][tid] + smS[2][tid] + smS[3][tid];
            float q = smQ[0][tid] + smQ[1][tid] + smQ[2][tid] + smQ[3][tid];
            atomicAdd(&stats[tid], s);
            atomicAdd(&stats[128 + tid], q);
        }
    }
}

// ---------------------------------------------------------------------------
// BN finalize (per-block, from stats) + affine + ReLU in place; also hs = dinv*h.
__global__ __launch_bounds__(256) void bn_apply_k(
    ushort* __restrict__ hb, ushort* __restrict__ hsb,
    const float* __restrict__ stats, const float* __restrict__ gamma,
    const float* __restrict__ beta, const float* __restrict__ dinv,
    float inv_n, int n64) {
    __shared__ float sp[256];
    int tid = threadIdx.x;
    if (tid < 128) {
        float mean = stats[tid] * inv_n;
        float var = stats[128 + tid] * inv_n - mean * mean;
        float sc = gamma[tid] * rsqrtf(var + BN_EPS);
        sp[tid] = sc;
        sp[128 + tid] = beta[tid] - mean * sc;
    }
    __syncthreads();
    int i = blockIdx.x * 256 + tid;
    if (i >= n64) return;
    int c2 = (i & 63) * 2;
    int row = i >> 6;
    uint v = ((uint*)hb)[i];
    float f0 = fmaxf(bf_lo(v) * sp[c2]     + sp[128 + c2],     0.f);
    float f1 = fmaxf(bf_hi(v) * sp[c2 + 1] + sp[128 + c2 + 1], 0.f);
    ((uint*)hb)[i] = pack2(f0, f1);
    float d = dinv[row];
    ((uint*)hsb)[i] = pack2(f0 * d, f1 * d);
}

// ---------------------------------------------------------------------------
extern "C" void kernel_launch(void* const* d_in, const int* in_sizes, int n_in,
                              void* d_out, int out_size, void* d_ws, size_t ws_size,
                              hipStream_t stream) {
    const float* x = (const float*)d_in[0];
    const int* edge_index = (const int*)d_in[1];
    const float* W1_0 = (const float*)d_in[2];
    const float* W1_1 = (const float*)d_in[3];
    const float* b1 = (const float*)d_in[4];
    const float* gamma = (const float*)d_in[5];
    const float* beta = (const float*)d_in[6];
    const float* Wmu_0 = (const float*)d_in[7];
    const float* Wmu_1 = (const float*)d_in[8];
    const float* b_mu = (const float*)d_in[9];
    const float* Wls_0 = (const float*)d_in[10];
    const float* Wls_1 = (const float*)d_in[11];
    const float* b_ls = (const float*)d_in[12];

    const int N = in_sizes[0] / IN_C;   // 50000
    const int E = in_sizes[1] / 2;      // 800000
    const int* src = edge_index;
    const int* dst = edge_index + E;

    char* w = (char*)d_ws;
    auto alloc = [&](size_t bytes) {
        char* p = w;
        w += (bytes + 15) & ~(size_t)15;
        return p;
    };
    float* stats = (float*)alloc(256 * 4);           // zeroed by count_k
    int* row_ptr = (int*)alloc((size_t)(N + 1) * 4);
    int* bsum    = (int*)alloc(256 * 4);
    float* dinv  = (float*)alloc((size_t)N * 4);
    int* cnt_dst = (int*)alloc((size_t)N * 4);
    int* col     = (int*)alloc((size_t)E * 4);
    int* hsrc_part = (int*)alloc((size_t)CS_C * N * 4);   // 6.4 MB
    int* hdst_part = (int*)alloc((size_t)CS_C * N * 4);   // 6.4 MB (-> offsets)
    ushort* x_bf  = (ushort*)alloc((size_t)N * 128 * 2);
    ushort* xs_bf = (ushort*)alloc((size_t)N * 128 * 2);  // reused as hs
    ushort* xp_bf = (ushort*)alloc((size_t)N * 128 * 2);  // reused as hp
    ushort* h_bf  = (ushort*)alloc((size_t)N * 128 * 2);
    ushort* Wt1   = (ushort*)alloc(128 * 256 * 2);
    ushort* Wt2   = (ushort*)alloc(128 * 256 * 2);
    float* bias1  = (float*)alloc(128 * 4);
    float* bias2  = (float*)alloc(128 * 4);

    ushort* hs_bf = xs_bf;
    ushort* hp_bf = xp_bf;

    float* out_mu = (float*)d_out;
    float* out_ls = out_mu + (size_t)N * OUT_C;

    int chunk = (E + CS_C - 1) / CS_C;    // 25000
    int range = (N + CS_R - 1) / CS_R;    // 6250
    int NBLK = (N + 255) / 256;           // 196 node blocks
    int nb_conv = (N * 64 + 255) / 256;   // 12500

    hist_k<<<CS_R * CS_C, 1024, 0, stream>>>(src, dst, hsrc_part, hdst_part, N, E, chunk, range);
    count_k<<<NBLK, 256, 0, stream>>>(hsrc_part, hdst_part, dinv, cnt_dst, bsum, stats, N);
    bscan_k<<<1, 256, 0, stream>>>(bsum, NBLK);
    phase3_k<<<NBLK, 256, 0, stream>>>(cnt_dst, bsum, row_ptr, hdst_part, N);
    scatter_k<<<CS_R * CS_C, 1024, 0, stream>>>(src, dst, hdst_part, col, N, E, chunk, range);

    convert_prep_k<<<nb_conv + 256, 256, 0, stream>>>(
        x, dinv, x_bf, xs_bf, N * 64, nb_conv,
        W1_0, W1_1, b1, Wmu_0, Wmu_1, b_mu, Wls_0, Wls_1, b_ls,
        Wt1, Wt2, bias1, bias2);

    int pb = (N + 3) / 4;
    propagate4_k<<<pb, 256, 0, stream>>>((const uint4*)xs_bf, (uint4*)xp_bf,
                                         row_ptr, col, dinv, N);

    int gb = (N + 63) / 64;
    gemm_mfma_k<0><<<gb, 256, 0, stream>>>(x_bf, xp_bf, Wt1, bias1, h_bf,
                                           nullptr, nullptr, stats, N);

    bn_apply_k<<<(N * 64 + 255) / 256, 256, 0, stream>>>(h_bf, hs_bf, stats, gamma, beta,
                                                         dinv, 1.f / (float)N, N * 64);

    propagate4_k<<<pb, 256, 0, stream>>>((const uint4*)hs_bf, (uint4*)hp_bf,
                                         row_ptr, col, dinv, N);

    gemm_mfma_k<1><<<gb, 256, 0, stream>>>(h_bf, hp_bf, Wt2, bias2, nullptr,
                                           out_mu, out_ls, stats, N);
}